// Round 11
// baseline (228.250 us; speedup 1.0000x reference)
//
#include <hip/hip_runtime.h>
#include <hip/hip_bf16.h>

#define N_NODES   4096
#define E_EDGES   262144
#define IN_DIM    256
#define EDGE_DIM  16
#define NAF       16
#define LATENT    128
#define NBT       5

#define LATENT_OFF 0
#define ATOMS_OFF  (N_NODES * LATENT)                 // 524288
#define BONDS_OFF  (ATOMS_OFF + N_NODES * NAF)        // 589824

// hash table: 2^20 u64 slots = 8 MB, load factor 0.25
#define TBITS 20
#define TSIZE (1u << TBITS)
#define TMASK (TSIZE - 1u)

typedef float    f32x4  __attribute__((ext_vector_type(4)));
typedef float    f32x4v __attribute__((ext_vector_type(4)));
typedef short    bf16x8 __attribute__((ext_vector_type(8)));
typedef unsigned u32x2  __attribute__((ext_vector_type(2)));
typedef unsigned u32x4  __attribute__((ext_vector_type(4)));

__device__ __forceinline__ float silu_f(float x) {
    return x / (1.0f + __expf(-x));
}

// HW packed f32->bf16 RNE (gfx950 v_cvt_pk_bf16_f32), bit-trick fallback.
__device__ __forceinline__ unsigned pack_bf16x2(float lo, float hi) {
#if __has_builtin(__builtin_amdgcn_cvt_pk_bf16_f32)
    typedef __bf16 bf16x2_t __attribute__((ext_vector_type(2)));
    union { bf16x2_t v; unsigned u; } c;
    c.v = __builtin_amdgcn_cvt_pk_bf16_f32(lo, hi);
    return c.u;
#else
    union { float f; unsigned u; } a, b;
    a.f = lo; b.f = hi;
    const unsigned ra = (a.u + 0x7FFFu + ((a.u >> 16) & 1u)) >> 16;
    const unsigned rb = (b.u + 0x7FFFu + ((b.u >> 16) & 1u)) >> 16;
    return ra | (rb << 16);
#endif
}

__device__ __forceinline__ float bf_lo(unsigned u) {
    union { unsigned x; float f; } c; c.x = u << 16; return c.f;
}
__device__ __forceinline__ float bf_hi(unsigned u) {
    union { unsigned x; float f; } c; c.x = u & 0xFFFF0000u; return c.f;
}

__device__ __forceinline__ int hlookup(const unsigned long long* __restrict__ tab,
                                       unsigned key) {
    unsigned h = (key * 2654435761u) >> (32 - TBITS);
    while (true) {
        const unsigned long long cur = tab[h];
        if (cur == 0ULL) return -1;
        if ((unsigned)(cur >> 18) == key + 1u) return (int)(cur & 0x3FFFFu);
        h = (h + 1u) & TMASK;
    }
}

// ---------------------------------------------------------------------------
// k_prep: ONE kernel for all preparation (unchanged from R10).
//   blocks 0..511    : k12 — s_act(bf16) = silu(s@Wsh^T+b); atoms/latent out
//   blocks 512..1535 : hash insert (winner = max edge id per (j,i) key)
//   block  1536      : prepack Wb/bb and Wbs into MFMA A-frag records
// ---------------------------------------------------------------------------
__global__ __launch_bounds__(256) void k_prep(const float* __restrict__ s,
                                              const float* __restrict__ Wsh,
                                              const float* __restrict__ bsh,
                                              const float* __restrict__ Wa,
                                              const float* __restrict__ ba,
                                              const int* __restrict__ eidx,
                                              const float* __restrict__ Wb,
                                              const float* __restrict__ bb,
                                              const float* __restrict__ Wbs,
                                              unsigned* __restrict__ sact16,
                                              unsigned long long* __restrict__ tab,
                                              u32x4* __restrict__ A1pre,
                                              u32x4* __restrict__ A2pre,
                                              float* __restrict__ out) {
    __shared__ float sl[8][32];
    __shared__ float st[8][IN_DIM];
    const int blk = blockIdx.x;
    const int c   = threadIdx.x;

    if (blk >= 512) {
        if (blk < 1536) {
            const int k = (blk - 512) * 256 + c;
            const unsigned j = (unsigned)eidx[k];
            const unsigned i = (unsigned)eidx[E_EDGES + k];
            const unsigned key = (j << 12) | i;
            const unsigned long long mine =
                ((unsigned long long)(key + 1u) << 18) | (unsigned)k;
            unsigned h = (key * 2654435761u) >> (32 - TBITS);
            while (true) {
                unsigned long long cur = tab[h];
                if (cur == 0ULL) {
                    const unsigned long long old = atomicCAS(&tab[h], 0ULL, mine);
                    if (old == 0ULL) return;
                    cur = old;
                }
                if ((unsigned)(cur >> 18) == key + 1u) {
                    atomicMax(&tab[h], mine);
                    return;
                }
                h = (h + 1u) & TMASK;
            }
        } else {
#pragma unroll
            for (int ee = 0; ee < 4; ++ee) {
                const int idx  = c + 256 * ee;
                const int g    = idx >> 6;
                const int lane = idx & 63;
                const int m    = lane & 15;
                const int q    = lane >> 4;

                const float4 w = *(const float4*)(Wb + (16 * g + m) * EDGE_DIM + 4 * q);
                u32x4 r1;
                r1.x = pack_bf16x2(w.x, w.y);
                r1.y = pack_bf16x2(w.z, w.w);
                r1.z = pack_bf16x2(bb[16 * g + m], 0.0f);
                r1.w = 0u;
                A1pre[idx] = r1;

                u32x4 r2;
                if (m < NBT) {
                    const float4 ws = *(const float4*)(Wbs + m * IN_DIM + 16 * g + 4 * q);
                    r2.x = pack_bf16x2(ws.x, ws.y);
                    r2.y = pack_bf16x2(ws.z, ws.w);
                } else {
                    r2.x = 0u; r2.y = 0u;
                }
                r2.z = 0u; r2.w = 0u;
                A2pre[idx] = r2;
            }
        }
        return;
    }

    // ---- k12 body: rows r0..r0+7
    const int r0 = blk * 8;

    float acc[8];
    const float bias = bsh[c];
#pragma unroll
    for (int r = 0; r < 8; ++r) acc[r] = bias;

    for (int k0 = 0; k0 < IN_DIM; k0 += 32) {
        sl[c >> 5][c & 31] = s[(r0 + (c >> 5)) * IN_DIM + k0 + (c & 31)];
        __syncthreads();

        float4 w4[8];
        const float4* wp = (const float4*)(Wsh + c * IN_DIM + k0);
#pragma unroll
        for (int q = 0; q < 8; ++q) w4[q] = wp[q];
        const float* wf = (const float*)w4;
#pragma unroll
        for (int r = 0; r < 8; ++r) {
            const float4* srow = (const float4*)sl[r];
            float a = acc[r];
#pragma unroll
            for (int q = 0; q < 8; ++q) {
                const float4 sv = srow[q];
                a += sv.x * wf[q * 4 + 0];
                a += sv.y * wf[q * 4 + 1];
                a += sv.z * wf[q * 4 + 2];
                a += sv.w * wf[q * 4 + 3];
            }
            acc[r] = a;
        }
        __syncthreads();
    }
#pragma unroll
    for (int r = 0; r < 8; ++r) st[r][c] = silu_f(acc[r]);
    __syncthreads();

    if (c < 128) {
#pragma unroll
        for (int r = 0; r < 8; ++r)
            sact16[(size_t)(r0 + r) * 128 + c] =
                pack_bf16x2(st[r][2 * c], st[r][2 * c + 1]);
    }

    const bool active = (c < (NAF + LATENT));
    float acc2[8];
    const float bias2 = active ? ba[c] : 0.0f;
#pragma unroll
    for (int r = 0; r < 8; ++r) acc2[r] = bias2;

    if (active) {
        for (int k0 = 0; k0 < IN_DIM; k0 += 32) {
            float4 w4[8];
            const float4* wp = (const float4*)(Wa + c * IN_DIM + k0);
#pragma unroll
            for (int q = 0; q < 8; ++q) w4[q] = wp[q];
            const float* wf = (const float*)w4;
#pragma unroll
            for (int r = 0; r < 8; ++r) {
                const float4* srow = (const float4*)(st[r] + k0);
                float a = acc2[r];
#pragma unroll
                for (int q = 0; q < 8; ++q) {
                    const float4 sv = srow[q];
                    a += sv.x * wf[q * 4 + 0];
                    a += sv.y * wf[q * 4 + 1];
                    a += sv.z * wf[q * 4 + 2];
                    a += sv.w * wf[q * 4 + 3];
                }
                acc2[r] = a;
            }
        }
#pragma unroll
        for (int r = 0; r < 8; ++r) {
            const int row = r0 + r;
            if (c < NAF) out[ATOMS_OFF + row * NAF + c] = acc2[r];
            else         out[LATENT_OFF + row * LATENT + (c - NAF)] = acc2[r];
        }
    }
}

// ---------------------------------------------------------------------------
// K4: zero-LDS MFMA edge kernel — TWO independent 16-edge tiles per wave,
// chains interleaved for ILP (R10 analysis: latency-bound, ~4k-cyc dependent
// chain per tile, insufficient wave overlap at ~6 waves/SIMD).
// Per-chain structure unchanged from R9/R10 (verified correct).
// Grid: 2048 blocks x 256 = 8192 waves x 2 tiles x 16 edges = 262144.
// ---------------------------------------------------------------------------
__global__ __launch_bounds__(256, 6) void k_edges_mfma(const int* __restrict__ eidx,
                                                       const float* __restrict__ e,
                                                       const unsigned long long* __restrict__ tab,
                                                       const unsigned* __restrict__ sact16,
                                                       const u32x4* __restrict__ A1pre,
                                                       const u32x4* __restrict__ A2pre,
                                                       const float* __restrict__ bbs,
                                                       float* __restrict__ out) {
    const int lane = threadIdx.x & 63;
    const int wv   = threadIdx.x >> 6;
    const int m    = lane & 15;   // edge-within-tile (cols of D)
    const int q    = lane >> 4;   // quad (rows 4q+r of D)
    const int base = __builtin_amdgcn_readfirstlane((blockIdx.x * 4 + wv) * 32);

    const short one_q0 = (q == 0) ? (short)0x3F80 : (short)0;  // bf16(1.0)

    f32x4v acc_init;
#pragma unroll
    for (int r = 0; r < 4; ++r) {
        const int bond = 4 * q + r;
        acc_init[r] = (bond < NBT) ? bbs[bond] : 0.0f;
    }

    // ---- preamble: both tiles' probes issued together ----
    int k0c[2];
    k0c[0] = base;
    k0c[1] = base + 16;

    unsigned jv[2], iv[2];
#pragma unroll
    for (int t = 0; t < 2; ++t) {
        jv[t] = (unsigned)eidx[k0c[t] + m];
        iv[t] = (unsigned)eidx[E_EDGES + k0c[t] + m];
    }

    unsigned wfv[2]; int wrv[2];
#pragma unroll
    for (int t = 0; t < 2; ++t) {
        wfv[t] = (unsigned)hlookup(tab, (jv[t] << 12) | iv[t]);
        wrv[t] = hlookup(tab, (iv[t] << 12) | jv[t]);
    }

    union { bf16x8 v; short s[8]; unsigned u[4]; } B1[2];
#pragma unroll
    for (int t = 0; t < 2; ++t) {
        f32x4 es = *(const f32x4*)(e + (size_t)wfv[t] * EDGE_DIM + 4 * q);
        if (wrv[t] >= 0)
            es += *(const f32x4*)(e + (size_t)wrv[t] * EDGE_DIM + 4 * q);
        es *= 0.5f;
        B1[t].u[0] = pack_bf16x2(es[0], es[1]);
        B1[t].u[1] = pack_bf16x2(es[2], es[3]);
        B1[t].s[4] = one_q0; B1[t].s[5] = 0;
        B1[t].u[3] = 0u;
    }

    const unsigned* si0 = sact16 + (size_t)iv[0] * 128 + 2 * q;
    const unsigned* sj0 = sact16 + (size_t)jv[0] * 128 + 2 * q;
    const unsigned* si1 = sact16 + (size_t)iv[1] * 128 + 2 * q;
    const unsigned* sj1 = sact16 + (size_t)jv[1] * 128 + 2 * q;
    const u32x4* a1p = A1pre + lane;
    const u32x4* a2p = A2pre + lane;

    f32x4v acc0a = acc_init, acc1a = {0.0f, 0.0f, 0.0f, 0.0f};
    f32x4v acc0b = acc_init, acc1b = {0.0f, 0.0f, 0.0f, 0.0f};

#pragma unroll
    for (int qt = 0; qt < 4; ++qt) {
        // issue all 16 s_act loads of this quarter (both chains) up front
        u32x2 vi0[4], vj0[4], vi1[4], vj1[4];
#pragma unroll
        for (int t = 0; t < 4; ++t) {
            const int g = 4 * qt + t;
            vi0[t] = *(const u32x2*)(si0 + 8 * g);
            vj0[t] = *(const u32x2*)(sj0 + 8 * g);
            vi1[t] = *(const u32x2*)(si1 + 8 * g);
            vj1[t] = *(const u32x2*)(sj1 + 8 * g);
        }
#pragma unroll
        for (int t = 0; t < 4; ++t) {
            const int g = 4 * qt + t;
            union { u32x4 r; bf16x8 v; } A1, A2;
            A1.r = a1p[g * 64];
            A2.r = a2p[g * 64];

            // ---- chain A
            f32x4v C1a;
            C1a[0] = bf_lo(vi0[t].x) + bf_lo(vj0[t].x);
            C1a[1] = bf_hi(vi0[t].x) + bf_hi(vj0[t].x);
            C1a[2] = bf_lo(vi0[t].y) + bf_lo(vj0[t].y);
            C1a[3] = bf_hi(vi0[t].y) + bf_hi(vj0[t].y);
            const f32x4v Pa = __builtin_amdgcn_mfma_f32_16x16x32_bf16(A1.v, B1[0].v, C1a, 0, 0, 0);

            // ---- chain B
            f32x4v C1b;
            C1b[0] = bf_lo(vi1[t].x) + bf_lo(vj1[t].x);
            C1b[1] = bf_hi(vi1[t].x) + bf_hi(vj1[t].x);
            C1b[2] = bf_lo(vi1[t].y) + bf_lo(vj1[t].y);
            C1b[3] = bf_hi(vi1[t].y) + bf_hi(vj1[t].y);
            const f32x4v Pb = __builtin_amdgcn_mfma_f32_16x16x32_bf16(A1.v, B1[1].v, C1b, 0, 0, 0);

            union { bf16x8 v; unsigned u[4]; } B2a, B2b;
            B2a.u[0] = pack_bf16x2(silu_f(Pa[0]), silu_f(Pa[1]));
            B2a.u[1] = pack_bf16x2(silu_f(Pa[2]), silu_f(Pa[3]));
            B2a.u[2] = 0u; B2a.u[3] = 0u;
            B2b.u[0] = pack_bf16x2(silu_f(Pb[0]), silu_f(Pb[1]));
            B2b.u[1] = pack_bf16x2(silu_f(Pb[2]), silu_f(Pb[3]));
            B2b.u[2] = 0u; B2b.u[3] = 0u;

            if (g & 1) {
                acc1a = __builtin_amdgcn_mfma_f32_16x16x32_bf16(A2.v, B2a.v, acc1a, 0, 0, 0);
                acc1b = __builtin_amdgcn_mfma_f32_16x16x32_bf16(A2.v, B2b.v, acc1b, 0, 0, 0);
            } else {
                acc0a = __builtin_amdgcn_mfma_f32_16x16x32_bf16(A2.v, B2a.v, acc0a, 0, 0, 0);
                acc0b = __builtin_amdgcn_mfma_f32_16x16x32_bf16(A2.v, B2b.v, acc0b, 0, 0, 0);
            }
        }
    }

    const f32x4v accA = acc0a + acc1a;
    const f32x4v accB = acc0b + acc1b;
    float* opA = out + BONDS_OFF + (size_t)(k0c[0] + m) * NBT;
    float* opB = out + BONDS_OFF + (size_t)(k0c[1] + m) * NBT;
    if (q == 0) {
        __builtin_nontemporal_store(accA[0], opA + 0);
        __builtin_nontemporal_store(accA[1], opA + 1);
        __builtin_nontemporal_store(accA[2], opA + 2);
        __builtin_nontemporal_store(accA[3], opA + 3);
        __builtin_nontemporal_store(accB[0], opB + 0);
        __builtin_nontemporal_store(accB[1], opB + 1);
        __builtin_nontemporal_store(accB[2], opB + 2);
        __builtin_nontemporal_store(accB[3], opB + 3);
    } else if (q == 1) {
        __builtin_nontemporal_store(accA[0], opA + 4);
        __builtin_nontemporal_store(accB[0], opB + 4);
    }
}

// ---------------------------------------------------------------------------
extern "C" void kernel_launch(void* const* d_in, const int* in_sizes, int n_in,
                              void* d_out, int out_size, void* d_ws, size_t ws_size,
                              hipStream_t stream) {
    const float* s   = (const float*)d_in[0];
    const float* e   = (const float*)d_in[1];
    const int*   eix = (const int*)d_in[3];
    const float* Wsh = (const float*)d_in[4];
    const float* bsh = (const float*)d_in[5];
    const float* Wb  = (const float*)d_in[6];
    const float* bbo = (const float*)d_in[7];
    const float* Wbs = (const float*)d_in[8];
    const float* bbs = (const float*)d_in[9];
    const float* Wa  = (const float*)d_in[10];
    const float* ba  = (const float*)d_in[11];
    float* out = (float*)d_out;

    char* ws = (char*)d_ws;
    unsigned*           sact16 = (unsigned*)ws;                   // 2 MB @ 0
    u32x4*              A1pre  = (u32x4*)(ws + (2u << 20));       // 16 KB
    u32x4*              A2pre  = (u32x4*)(ws + (2u << 20) + 16384);
    unsigned long long* tab    = (unsigned long long*)(ws + (3u << 20)); // 8 MB

    (void)hipMemsetAsync(tab, 0x00, TSIZE * sizeof(unsigned long long), stream);

    k_prep<<<1537, 256, 0, stream>>>(s, Wsh, bsh, Wa, ba, eix, Wb, bbo, Wbs,
                                     sact16, tab, A1pre, A2pre, out);
    k_edges_mfma<<<2048, 256, 0, stream>>>(eix, e, tab, sact16,
                                           A1pre, A2pre, bbs, out);
}

// Round 12
// 210.058 us; speedup vs baseline: 1.0866x; 1.0866x over previous
//
#include <hip/hip_runtime.h>
#include <hip/hip_bf16.h>

#define N_NODES   4096
#define E_EDGES   262144
#define IN_DIM    256
#define EDGE_DIM  16
#define NAF       16
#define LATENT    128
#define NBT       5

#define LATENT_OFF 0
#define ATOMS_OFF  (N_NODES * LATENT)                 // 524288
#define BONDS_OFF  (ATOMS_OFF + N_NODES * NAF)        // 589824

// hash table: 2^20 u64 slots = 8 MB, load factor 0.25
#define TBITS 20
#define TSIZE (1u << TBITS)
#define TMASK (TSIZE - 1u)

typedef float    f32x4  __attribute__((ext_vector_type(4)));
typedef float    f32x4v __attribute__((ext_vector_type(4)));
typedef short    bf16x8 __attribute__((ext_vector_type(8)));
typedef unsigned u32x2  __attribute__((ext_vector_type(2)));
typedef unsigned u32x4  __attribute__((ext_vector_type(4)));

__device__ __forceinline__ float silu_f(float x) {
    return x / (1.0f + __expf(-x));
}

// HW packed f32->bf16 RNE (gfx950 v_cvt_pk_bf16_f32), bit-trick fallback.
__device__ __forceinline__ unsigned pack_bf16x2(float lo, float hi) {
#if __has_builtin(__builtin_amdgcn_cvt_pk_bf16_f32)
    typedef __bf16 bf16x2_t __attribute__((ext_vector_type(2)));
    union { bf16x2_t v; unsigned u; } c;
    c.v = __builtin_amdgcn_cvt_pk_bf16_f32(lo, hi);
    return c.u;
#else
    union { float f; unsigned u; } a, b;
    a.f = lo; b.f = hi;
    const unsigned ra = (a.u + 0x7FFFu + ((a.u >> 16) & 1u)) >> 16;
    const unsigned rb = (b.u + 0x7FFFu + ((b.u >> 16) & 1u)) >> 16;
    return ra | (rb << 16);
#endif
}

__device__ __forceinline__ float bf_lo(unsigned u) {
    union { unsigned x; float f; } c; c.x = u << 16; return c.f;
}
__device__ __forceinline__ float bf_hi(unsigned u) {
    union { unsigned x; float f; } c; c.x = u & 0xFFFF0000u; return c.f;
}

// async gather: per-lane 16B global -> LDS[uniform base + lane*16]
__device__ __forceinline__ void gld_lds16(const void* g, void* l) {
    __builtin_amdgcn_global_load_lds(
        (const __attribute__((address_space(1))) unsigned*)g,
        (__attribute__((address_space(3))) unsigned*)l, 16, 0, 0);
}

__device__ __forceinline__ int hlookup(const unsigned long long* __restrict__ tab,
                                       unsigned key) {
    unsigned h = (key * 2654435761u) >> (32 - TBITS);
    while (true) {
        const unsigned long long cur = tab[h];
        if (cur == 0ULL) return -1;
        if ((unsigned)(cur >> 18) == key + 1u) return (int)(cur & 0x3FFFFu);
        h = (h + 1u) & TMASK;
    }
}

// ---------------------------------------------------------------------------
// k_prep: ONE kernel for all preparation.
//   blocks 0..511    : k12 — sact16 = bf16(silu(s@Wsh^T+b) + bb/2); atoms out
//   blocks 512..1535 : hash insert (winner = max edge id per (j,i) key)
//   block  1536      : prepack merged A1A2 MFMA frag records
// ---------------------------------------------------------------------------
__global__ __launch_bounds__(256) void k_prep(const float* __restrict__ s,
                                              const float* __restrict__ Wsh,
                                              const float* __restrict__ bsh,
                                              const float* __restrict__ Wa,
                                              const float* __restrict__ ba,
                                              const int* __restrict__ eidx,
                                              const float* __restrict__ Wb,
                                              const float* __restrict__ bb,
                                              const float* __restrict__ Wbs,
                                              unsigned* __restrict__ sact16,
                                              unsigned long long* __restrict__ tab,
                                              u32x4* __restrict__ A12pre,
                                              float* __restrict__ out) {
    __shared__ float sl[8][32];
    __shared__ float st[8][IN_DIM];
    const int blk = blockIdx.x;
    const int c   = threadIdx.x;

    if (blk >= 512) {
        if (blk < 1536) {
            const int k = (blk - 512) * 256 + c;
            const unsigned j = (unsigned)eidx[k];
            const unsigned i = (unsigned)eidx[E_EDGES + k];
            const unsigned key = (j << 12) | i;
            const unsigned long long mine =
                ((unsigned long long)(key + 1u) << 18) | (unsigned)k;
            unsigned h = (key * 2654435761u) >> (32 - TBITS);
            while (true) {
                unsigned long long cur = tab[h];
                if (cur == 0ULL) {
                    const unsigned long long old = atomicCAS(&tab[h], 0ULL, mine);
                    if (old == 0ULL) return;
                    cur = old;
                }
                if ((unsigned)(cur >> 18) == key + 1u) {
                    atomicMax(&tab[h], mine);
                    return;
                }
                h = (h + 1u) & TMASK;
            }
        } else {
            // merged A1A2 records: {Wb pair, Wb pair, Wbs pair, Wbs pair}
#pragma unroll
            for (int ee = 0; ee < 4; ++ee) {
                const int idx  = c + 256 * ee;
                const int g    = idx >> 6;
                const int lane = idx & 63;
                const int m    = lane & 15;
                const int q    = lane >> 4;

                const float4 w = *(const float4*)(Wb + (16 * g + m) * EDGE_DIM + 4 * q);
                u32x4 r;
                r.x = pack_bf16x2(w.x, w.y);
                r.y = pack_bf16x2(w.z, w.w);
                if (m < NBT) {
                    const float4 ws = *(const float4*)(Wbs + m * IN_DIM + 16 * g + 4 * q);
                    r.z = pack_bf16x2(ws.x, ws.y);
                    r.w = pack_bf16x2(ws.z, ws.w);
                } else {
                    r.z = 0u; r.w = 0u;
                }
                A12pre[idx] = r;
            }
        }
        return;
    }

    // ---- k12 body: rows r0..r0+7
    const int r0 = blk * 8;

    float acc[8];
    const float bias = bsh[c];
#pragma unroll
    for (int r = 0; r < 8; ++r) acc[r] = bias;

    for (int k0 = 0; k0 < IN_DIM; k0 += 32) {
        sl[c >> 5][c & 31] = s[(r0 + (c >> 5)) * IN_DIM + k0 + (c & 31)];
        __syncthreads();

        float4 w4[8];
        const float4* wp = (const float4*)(Wsh + c * IN_DIM + k0);
#pragma unroll
        for (int q = 0; q < 8; ++q) w4[q] = wp[q];
        const float* wf = (const float*)w4;
#pragma unroll
        for (int r = 0; r < 8; ++r) {
            const float4* srow = (const float4*)sl[r];
            float a = acc[r];
#pragma unroll
            for (int q = 0; q < 8; ++q) {
                const float4 sv = srow[q];
                a += sv.x * wf[q * 4 + 0];
                a += sv.y * wf[q * 4 + 1];
                a += sv.z * wf[q * 4 + 2];
                a += sv.w * wf[q * 4 + 3];
            }
            acc[r] = a;
        }
        __syncthreads();
    }
#pragma unroll
    for (int r = 0; r < 8; ++r) st[r][c] = silu_f(acc[r]);
    __syncthreads();

    // bf16 s_act with bb/2 folded: (s_i+bb/2)+(s_j+bb/2) = s_i+s_j+bb
    if (c < 128) {
        const float b0 = 0.5f * bb[2 * c];
        const float b1 = 0.5f * bb[2 * c + 1];
#pragma unroll
        for (int r = 0; r < 8; ++r)
            sact16[(size_t)(r0 + r) * 128 + c] =
                pack_bf16x2(st[r][2 * c] + b0, st[r][2 * c + 1] + b1);
    }

    const bool active = (c < (NAF + LATENT));
    float acc2[8];
    const float bias2 = active ? ba[c] : 0.0f;
#pragma unroll
    for (int r = 0; r < 8; ++r) acc2[r] = bias2;

    if (active) {
        for (int k0 = 0; k0 < IN_DIM; k0 += 32) {
            float4 w4[8];
            const float4* wp = (const float4*)(Wa + c * IN_DIM + k0);
#pragma unroll
            for (int q = 0; q < 8; ++q) w4[q] = wp[q];
            const float* wf = (const float*)w4;
#pragma unroll
            for (int r = 0; r < 8; ++r) {
                const float4* srow = (const float4*)(st[r] + k0);
                float a = acc2[r];
#pragma unroll
                for (int q = 0; q < 8; ++q) {
                    const float4 sv = srow[q];
                    a += sv.x * wf[q * 4 + 0];
                    a += sv.y * wf[q * 4 + 1];
                    a += sv.z * wf[q * 4 + 2];
                    a += sv.w * wf[q * 4 + 3];
                }
                acc2[r] = a;
            }
        }
#pragma unroll
        for (int r = 0; r < 8; ++r) {
            const int row = r0 + r;
            if (c < NAF) out[ATOMS_OFF + row * NAF + c] = acc2[r];
            else         out[LATENT_OFF + row * LATENT + (c - NAF)] = acc2[r];
        }
    }
}

// ---------------------------------------------------------------------------
// K4: MFMA edge kernel with line-batched gathers (R11 diagnosis: L1/TA
// cacheline-throughput bound — dur invariant to TLP halving + ILP doubling).
// sact rows pulled via global_load_lds gather: lane(m,q) iter u fetches 16B
// chunk (4u+q) of row[m] -> each instruction touches each 64B line exactly
// once. C-init then via ds_read_b64 (LDS pipe, idle). Half-row double-pass
// keeps LDS at 8 KB/wave. bb folded into sact16; A1+A2 merged to one 16B rec.
// Grid: 4096 blocks x 256 = 16384 waves x 16 edges.
// ---------------------------------------------------------------------------
__global__ __launch_bounds__(256, 5) void k_edges_mfma(const int* __restrict__ eidx,
                                                       const float* __restrict__ e,
                                                       const unsigned long long* __restrict__ tab,
                                                       const unsigned* __restrict__ sact16,
                                                       const u32x4* __restrict__ A12pre,
                                                       const float* __restrict__ bbs,
                                                       float* __restrict__ out) {
    __shared__ unsigned lds_all[4][2048];   // 8 KB/wave: [0..1023]=node-i, [1024..2047]=node-j
    const int lane = threadIdx.x & 63;
    const int wv   = threadIdx.x >> 6;
    const int m    = lane & 15;   // edge-within-tile (cols of D)
    const int q    = lane >> 4;   // quad (rows 4q+r of D)
    const int k0   = __builtin_amdgcn_readfirstlane((blockIdx.x * 4 + wv) * 16);
    unsigned* myl = lds_all[wv];

    f32x4v acc_init;
#pragma unroll
    for (int r = 0; r < 4; ++r) {
        const int bond = 4 * q + r;
        acc_init[r] = (bond < NBT) ? bbs[bond] : 0.0f;
    }

    // ---- edge endpoints (lane m owns edge k0+m; same across quads)
    const unsigned j_m = (unsigned)eidx[k0 + m];
    const unsigned i_m = (unsigned)eidx[E_EDGES + k0 + m];

    const char* si_base = (const char*)(sact16 + (size_t)i_m * 128);  // 512 B rows
    const char* sj_base = (const char*)(sact16 + (size_t)j_m * 128);

    // ---- stage half 0 (channels 0..127): chunk (4u+q) of each half-row
#pragma unroll
    for (int u = 0; u < 4; ++u)
        gld_lds16(si_base + (4 * u + q) * 16, (char*)myl + u * 1024);
#pragma unroll
    for (int u = 0; u < 4; ++u)
        gld_lds16(sj_base + (4 * u + q) * 16, (char*)myl + 4096 + u * 1024);

    // ---- hash probes + e gather (overlap the staging)
    const unsigned wf = (unsigned)hlookup(tab, (j_m << 12) | i_m);
    const int      wr = hlookup(tab, (i_m << 12) | j_m);

    f32x4 es = *(const f32x4*)(e + (size_t)wf * EDGE_DIM + 4 * q);
    if (wr >= 0)
        es += *(const f32x4*)(e + (size_t)wr * EDGE_DIM + 4 * q);
    es *= 0.5f;

    union { bf16x8 v; unsigned u[4]; } B1;
    B1.u[0] = pack_bf16x2(es[0], es[1]);
    B1.u[1] = pack_bf16x2(es[2], es[3]);
    B1.u[2] = 0u; B1.u[3] = 0u;

    const u32x4* a12p = A12pre + lane;

    f32x4v acc0 = acc_init;
    f32x4v acc1 = {0.0f, 0.0f, 0.0f, 0.0f};

    const int qh  = q >> 1;        // chunk sub-index from quad
    const int qw  = 2 * (q & 1);   // word offset within 16 B
    const int mw  = m * 4;

    auto run_half = [&](int h) {
#pragma unroll
        for (int gp = 0; gp < 8; ++gp) {
            const int g     = 8 * h + gp;
            const int chunk = 2 * gp + qh;
            const int offw  = (chunk >> 2) * 256 + ((chunk & 3) * 16) * 4 + mw + qw;

            const u32x2 wi = *(const u32x2*)(myl + offw);
            const u32x2 wj = *(const u32x2*)(myl + 1024 + offw);

            f32x4v C1;
            C1[0] = bf_lo(wi.x) + bf_lo(wj.x);
            C1[1] = bf_hi(wi.x) + bf_hi(wj.x);
            C1[2] = bf_lo(wi.y) + bf_lo(wj.y);
            C1[3] = bf_hi(wi.y) + bf_hi(wj.y);

            const u32x4 rec = a12p[g * 64];
            union { bf16x8 v; unsigned u[4]; } A1, A2;
            A1.u[0] = rec.x; A1.u[1] = rec.y; A1.u[2] = 0u; A1.u[3] = 0u;
            A2.u[0] = rec.z; A2.u[1] = rec.w; A2.u[2] = 0u; A2.u[3] = 0u;

            const f32x4v P = __builtin_amdgcn_mfma_f32_16x16x32_bf16(A1.v, B1.v, C1, 0, 0, 0);

            union { bf16x8 v; unsigned u[4]; } B2;
            B2.u[0] = pack_bf16x2(silu_f(P[0]), silu_f(P[1]));
            B2.u[1] = pack_bf16x2(silu_f(P[2]), silu_f(P[3]));
            B2.u[2] = 0u; B2.u[3] = 0u;

            if (g & 1) acc1 = __builtin_amdgcn_mfma_f32_16x16x32_bf16(A2.v, B2.v, acc1, 0, 0, 0);
            else       acc0 = __builtin_amdgcn_mfma_f32_16x16x32_bf16(A2.v, B2.v, acc0, 0, 0, 0);
        }
    };

    __asm__ __volatile__("s_waitcnt vmcnt(0)" ::: "memory");
    run_half(0);

    // drain ds_reads of half 0, then restage half 1 (channels 128..255)
    __asm__ __volatile__("s_waitcnt lgkmcnt(0)" ::: "memory");
#pragma unroll
    for (int u = 0; u < 4; ++u)
        gld_lds16(si_base + 256 + (4 * u + q) * 16, (char*)myl + u * 1024);
#pragma unroll
    for (int u = 0; u < 4; ++u)
        gld_lds16(sj_base + 256 + (4 * u + q) * 16, (char*)myl + 4096 + u * 1024);
    __asm__ __volatile__("s_waitcnt vmcnt(0)" ::: "memory");
    run_half(1);

    const f32x4v accT = acc0 + acc1;
    float* op = out + BONDS_OFF + (size_t)(k0 + m) * NBT;
    if (q == 0) {
        __builtin_nontemporal_store(accT[0], op + 0);
        __builtin_nontemporal_store(accT[1], op + 1);
        __builtin_nontemporal_store(accT[2], op + 2);
        __builtin_nontemporal_store(accT[3], op + 3);
    } else if (q == 1) {
        __builtin_nontemporal_store(accT[0], op + 4);
    }
}

// ---------------------------------------------------------------------------
extern "C" void kernel_launch(void* const* d_in, const int* in_sizes, int n_in,
                              void* d_out, int out_size, void* d_ws, size_t ws_size,
                              hipStream_t stream) {
    const float* s   = (const float*)d_in[0];
    const float* e   = (const float*)d_in[1];
    const int*   eix = (const int*)d_in[3];
    const float* Wsh = (const float*)d_in[4];
    const float* bsh = (const float*)d_in[5];
    const float* Wb  = (const float*)d_in[6];
    const float* bbo = (const float*)d_in[7];
    const float* Wbs = (const float*)d_in[8];
    const float* bbs = (const float*)d_in[9];
    const float* Wa  = (const float*)d_in[10];
    const float* ba  = (const float*)d_in[11];
    float* out = (float*)d_out;

    char* ws = (char*)d_ws;
    unsigned*           sact16 = (unsigned*)ws;                   // 2 MB @ 0
    u32x4*              A12pre = (u32x4*)(ws + (2u << 20));       // 16 KB
    unsigned long long* tab    = (unsigned long long*)(ws + (3u << 20)); // 8 MB

    (void)hipMemsetAsync(tab, 0x00, TSIZE * sizeof(unsigned long long), stream);

    k_prep<<<1537, 256, 0, stream>>>(s, Wsh, bsh, Wa, ba, eix, Wb, bbo, Wbs,
                                     sact16, tab, A12pre, out);
    k_edges_mfma<<<4096, 256, 0, stream>>>(eix, e, tab, sact16,
                                           A12pre, bbs, out);
}

// Round 13
// 193.405 us; speedup vs baseline: 1.1802x; 1.0861x over previous
//
#include <hip/hip_runtime.h>
#include <hip/hip_bf16.h>

#define N_NODES   4096
#define E_EDGES   262144
#define IN_DIM    256
#define EDGE_DIM  16
#define NAF       16
#define LATENT    128
#define NBT       5

#define LATENT_OFF 0
#define ATOMS_OFF  (N_NODES * LATENT)                 // 524288
#define BONDS_OFF  (ATOMS_OFF + N_NODES * NAF)        // 589824

// hash table: 2^20 u64 slots = 8 MB, load factor 0.25
#define TBITS 20
#define TSIZE (1u << TBITS)
#define TMASK (TSIZE - 1u)

typedef float    f32x4  __attribute__((ext_vector_type(4)));
typedef float    f32x4v __attribute__((ext_vector_type(4)));
typedef short    bf16x8 __attribute__((ext_vector_type(8)));
typedef unsigned u32x2  __attribute__((ext_vector_type(2)));
typedef unsigned u32x4  __attribute__((ext_vector_type(4)));

__device__ __forceinline__ float silu_f(float x) {
    return x / (1.0f + __expf(-x));
}

// HW packed f32->bf16 RNE (gfx950 v_cvt_pk_bf16_f32), bit-trick fallback.
__device__ __forceinline__ unsigned pack_bf16x2(float lo, float hi) {
#if __has_builtin(__builtin_amdgcn_cvt_pk_bf16_f32)
    typedef __bf16 bf16x2_t __attribute__((ext_vector_type(2)));
    union { bf16x2_t v; unsigned u; } c;
    c.v = __builtin_amdgcn_cvt_pk_bf16_f32(lo, hi);
    return c.u;
#else
    union { float f; unsigned u; } a, b;
    a.f = lo; b.f = hi;
    const unsigned ra = (a.u + 0x7FFFu + ((a.u >> 16) & 1u)) >> 16;
    const unsigned rb = (b.u + 0x7FFFu + ((b.u >> 16) & 1u)) >> 16;
    return ra | (rb << 16);
#endif
}

__device__ __forceinline__ float bf_lo(unsigned u) {
    union { unsigned x; float f; } c; c.x = u << 16; return c.f;
}
__device__ __forceinline__ float bf_hi(unsigned u) {
    union { unsigned x; float f; } c; c.x = u & 0xFFFF0000u; return c.f;
}

// split fp32x8 into bf16 hi + bf16 lo fragments (x = hi + lo exactly to 2^-18)
__device__ __forceinline__ void split_bf16(const float4 x0, const float4 x1,
                                           bf16x8* hi, bf16x8* lo) {
    union { bf16x8 v; unsigned u[4]; } H, L;
    H.u[0] = pack_bf16x2(x0.x, x0.y);
    H.u[1] = pack_bf16x2(x0.z, x0.w);
    H.u[2] = pack_bf16x2(x1.x, x1.y);
    H.u[3] = pack_bf16x2(x1.z, x1.w);
    L.u[0] = pack_bf16x2(x0.x - bf_lo(H.u[0]), x0.y - bf_hi(H.u[0]));
    L.u[1] = pack_bf16x2(x0.z - bf_lo(H.u[1]), x0.w - bf_hi(H.u[1]));
    L.u[2] = pack_bf16x2(x1.x - bf_lo(H.u[2]), x1.y - bf_hi(H.u[2]));
    L.u[3] = pack_bf16x2(x1.z - bf_lo(H.u[3]), x1.w - bf_hi(H.u[3]));
    *hi = H.v; *lo = L.v;
}

// async gather: per-lane 16B global -> LDS[uniform base + lane*16]
__device__ __forceinline__ void gld_lds16(const void* g, void* l) {
    __builtin_amdgcn_global_load_lds(
        (const __attribute__((address_space(1))) unsigned*)g,
        (__attribute__((address_space(3))) unsigned*)l, 16, 0, 0);
}

__device__ __forceinline__ int hlookup(const unsigned long long* __restrict__ tab,
                                       unsigned key) {
    unsigned h = (key * 2654435761u) >> (32 - TBITS);
    while (true) {
        const unsigned long long cur = tab[h];
        if (cur == 0ULL) return -1;
        if ((unsigned)(cur >> 18) == key + 1u) return (int)(cur & 0x3FFFFu);
        h = (h + 1u) & TMASK;
    }
}

// ---------------------------------------------------------------------------
// k_gemm1: blocks 0..1023  : sact16 = bf16(silu(s@Wsh^T + bsh)), MFMA tiles,
//                            split-bf16 (3 MFMA/chunk) for fp32-grade accuracy
//          blocks 1024..2047: hash insert (winner = max edge id per key)
//          block  2048      : prepack A1pre/A2pre MFMA frag records (R9 form)
// ---------------------------------------------------------------------------
__global__ __launch_bounds__(256) void k_gemm1(const float* __restrict__ s,
                                               const float* __restrict__ Wsh,
                                               const float* __restrict__ bsh,
                                               const int* __restrict__ eidx,
                                               const float* __restrict__ Wb,
                                               const float* __restrict__ bb,
                                               const float* __restrict__ Wbs,
                                               unsigned short* __restrict__ sact16,
                                               unsigned long long* __restrict__ tab,
                                               u32x4* __restrict__ A1pre,
                                               u32x4* __restrict__ A2pre) {
    const int blk = blockIdx.x;
    const int c   = threadIdx.x;

    if (blk >= 1024) {
        if (blk < 2048) {
            // ---- hash insert
            const int k = (blk - 1024) * 256 + c;
            const unsigned j = (unsigned)eidx[k];
            const unsigned i = (unsigned)eidx[E_EDGES + k];
            const unsigned key = (j << 12) | i;
            const unsigned long long mine =
                ((unsigned long long)(key + 1u) << 18) | (unsigned)k;
            unsigned h = (key * 2654435761u) >> (32 - TBITS);
            while (true) {
                unsigned long long cur = tab[h];
                if (cur == 0ULL) {
                    const unsigned long long old = atomicCAS(&tab[h], 0ULL, mine);
                    if (old == 0ULL) return;
                    cur = old;
                }
                if ((unsigned)(cur >> 18) == key + 1u) {
                    atomicMax(&tab[h], mine);
                    return;
                }
                h = (h + 1u) & TMASK;
            }
        } else {
            // ---- prepack: A1 = {Wb pair, Wb pair, pk(bb,0), 0}; A2 = {Wbs pair x2, 0, 0}
#pragma unroll
            for (int ee = 0; ee < 4; ++ee) {
                const int idx  = c + 256 * ee;
                const int g    = idx >> 6;
                const int lane = idx & 63;
                const int m    = lane & 15;
                const int q    = lane >> 4;

                const float4 w = *(const float4*)(Wb + (16 * g + m) * EDGE_DIM + 4 * q);
                u32x4 r1;
                r1.x = pack_bf16x2(w.x, w.y);
                r1.y = pack_bf16x2(w.z, w.w);
                r1.z = pack_bf16x2(bb[16 * g + m], 0.0f);
                r1.w = 0u;
                A1pre[idx] = r1;

                u32x4 r2;
                if (m < NBT) {
                    const float4 ws = *(const float4*)(Wbs + m * IN_DIM + 16 * g + 4 * q);
                    r2.x = pack_bf16x2(ws.x, ws.y);
                    r2.y = pack_bf16x2(ws.z, ws.w);
                } else {
                    r2.x = 0u; r2.y = 0u;
                }
                r2.z = 0u; r2.w = 0u;
                A2pre[idx] = r2;
            }
        }
        return;
    }

    // ---- GEMM1 tile: wave -> (row_tile, col_tile); 256 x 16 tiles
    const int lane = c & 63;
    const int wv   = c >> 6;
    const int wave = blk * 4 + wv;
    const int m    = lane & 15;
    const int q    = lane >> 4;
    const int row0 = (wave >> 4) * 16;
    const int col0 = (wave & 15) * 16;

    f32x4v acc;
    {
        const float bias = bsh[col0 + m];
        acc[0] = bias; acc[1] = bias; acc[2] = bias; acc[3] = bias;
    }

    const float* ap = s   + (size_t)(row0 + m) * IN_DIM + 8 * q;
    const float* bp = Wsh + (size_t)(col0 + m) * IN_DIM + 8 * q;

#pragma unroll
    for (int c8 = 0; c8 < 8; ++c8) {
        const float4 a0 = *(const float4*)(ap + 32 * c8);
        const float4 a1 = *(const float4*)(ap + 32 * c8 + 4);
        const float4 b0 = *(const float4*)(bp + 32 * c8);
        const float4 b1 = *(const float4*)(bp + 32 * c8 + 4);
        bf16x8 Ah, Al, Bh, Bl;
        split_bf16(a0, a1, &Ah, &Al);
        split_bf16(b0, b1, &Bh, &Bl);
        acc = __builtin_amdgcn_mfma_f32_16x16x32_bf16(Ah, Bh, acc, 0, 0, 0);
        acc = __builtin_amdgcn_mfma_f32_16x16x32_bf16(Al, Bh, acc, 0, 0, 0);
        acc = __builtin_amdgcn_mfma_f32_16x16x32_bf16(Ah, Bl, acc, 0, 0, 0);
    }

    // D: col = col0+m, rows row0+4q+r -> pure silu, bf16 short stores
#pragma unroll
    for (int r = 0; r < 4; ++r) {
        const int row = row0 + 4 * q + r;
        const float v = silu_f(acc[r]);
        sact16[(size_t)row * IN_DIM + col0 + m] =
            (unsigned short)(pack_bf16x2(v, 0.0f) & 0xFFFFu);
    }
}

// ---------------------------------------------------------------------------
// K4: blocks 0..4095  : MFMA edge kernel (R12 gather staging + R9 bias form)
//     blocks 4096..4671: GEMM2 — atoms/latent = sact16@Wa^T + ba
//                        (A = bf16 sact16 direct; B = Wa split-bf16, 2 MFMA)
// ---------------------------------------------------------------------------
__global__ __launch_bounds__(256, 5) void k_edges_mfma(const int* __restrict__ eidx,
                                                       const float* __restrict__ e,
                                                       const unsigned long long* __restrict__ tab,
                                                       const unsigned short* __restrict__ sact16,
                                                       const u32x4* __restrict__ A1pre,
                                                       const u32x4* __restrict__ A2pre,
                                                       const float* __restrict__ bbs,
                                                       const float* __restrict__ Wa,
                                                       const float* __restrict__ ba,
                                                       float* __restrict__ out) {
    __shared__ unsigned lds_all[4][2048];   // 8 KB/wave (edge blocks only)
    const int blk  = blockIdx.x;
    const int lane = threadIdx.x & 63;
    const int wv   = threadIdx.x >> 6;
    const int m    = lane & 15;
    const int q    = lane >> 4;

    if (blk >= 4096) {
        // ---- GEMM2: wave -> (row_tile, col_tile) over 256 x 9 tiles
        const int wave = (blk - 4096) * 4 + wv;   // 0..2303
        const int rt = wave / 9;
        const int ct = wave - rt * 9;
        const int row0  = rt * 16;
        const int n_abs = ct * 16 + m;            // 0..143

        f32x4v acc;
        {
            const float bias = ba[n_abs];
            acc[0] = bias; acc[1] = bias; acc[2] = bias; acc[3] = bias;
        }

        const unsigned short* apu = sact16 + (size_t)(row0 + m) * IN_DIM + 8 * q;
        const float*          bp  = Wa + (size_t)n_abs * IN_DIM + 8 * q;

#pragma unroll
        for (int c8 = 0; c8 < 8; ++c8) {
            const bf16x8 A = *(const bf16x8*)(apu + 32 * c8);
            const float4 b0 = *(const float4*)(bp + 32 * c8);
            const float4 b1 = *(const float4*)(bp + 32 * c8 + 4);
            bf16x8 Bh, Bl;
            split_bf16(b0, b1, &Bh, &Bl);
            acc = __builtin_amdgcn_mfma_f32_16x16x32_bf16(A, Bh, acc, 0, 0, 0);
            acc = __builtin_amdgcn_mfma_f32_16x16x32_bf16(A, Bl, acc, 0, 0, 0);
        }
#pragma unroll
        for (int r = 0; r < 4; ++r) {
            const int row = row0 + 4 * q + r;
            if (n_abs < NAF)
                out[ATOMS_OFF + (size_t)row * NAF + n_abs] = acc[r];
            else
                out[LATENT_OFF + (size_t)row * LATENT + (n_abs - NAF)] = acc[r];
        }
        return;
    }

    // ---- edge tile
    const int k0 = __builtin_amdgcn_readfirstlane((blk * 4 + wv) * 16);
    unsigned* myl = lds_all[wv];
    const short one_q0 = (q == 0) ? (short)0x3F80 : (short)0;  // bf16(1.0)

    f32x4v acc_init;
#pragma unroll
    for (int r = 0; r < 4; ++r) {
        const int bond = 4 * q + r;
        acc_init[r] = (bond < NBT) ? bbs[bond] : 0.0f;
    }

    const unsigned j_m = (unsigned)eidx[k0 + m];
    const unsigned i_m = (unsigned)eidx[E_EDGES + k0 + m];

    const char* si_base = (const char*)(sact16 + (size_t)i_m * IN_DIM);  // 512 B rows
    const char* sj_base = (const char*)(sact16 + (size_t)j_m * IN_DIM);

    // stage half 0 (channels 0..127)
#pragma unroll
    for (int u = 0; u < 4; ++u)
        gld_lds16(si_base + (4 * u + q) * 16, (char*)myl + u * 1024);
#pragma unroll
    for (int u = 0; u < 4; ++u)
        gld_lds16(sj_base + (4 * u + q) * 16, (char*)myl + 4096 + u * 1024);

    // hash probes + e gather (overlap staging)
    const unsigned wf = (unsigned)hlookup(tab, (j_m << 12) | i_m);
    const int      wr = hlookup(tab, (i_m << 12) | j_m);

    f32x4 es = *(const f32x4*)(e + (size_t)wf * EDGE_DIM + 4 * q);
    if (wr >= 0)
        es += *(const f32x4*)(e + (size_t)wr * EDGE_DIM + 4 * q);
    es *= 0.5f;

    union { bf16x8 v; short s[8]; unsigned u[4]; } B1;
    B1.u[0] = pack_bf16x2(es[0], es[1]);
    B1.u[1] = pack_bf16x2(es[2], es[3]);
    B1.s[4] = one_q0; B1.s[5] = 0;
    B1.u[3] = 0u;

    const u32x4* a1p = A1pre + lane;
    const u32x4* a2p = A2pre + lane;

    f32x4v acc0 = acc_init;
    f32x4v acc1 = {0.0f, 0.0f, 0.0f, 0.0f};

    const int qh = q >> 1;
    const int qw = 2 * (q & 1);
    const int mw = m * 4;

    auto run_half = [&](int h) {
#pragma unroll
        for (int gp = 0; gp < 8; ++gp) {
            const int g     = 8 * h + gp;
            const int chunk = 2 * gp + qh;
            const int offw  = (chunk >> 2) * 256 + (chunk & 3) * 64 + mw + qw;

            const u32x2 wi = *(const u32x2*)(myl + offw);
            const u32x2 wj = *(const u32x2*)(myl + 1024 + offw);

            f32x4v C1;
            C1[0] = bf_lo(wi.x) + bf_lo(wj.x);
            C1[1] = bf_hi(wi.x) + bf_hi(wj.x);
            C1[2] = bf_lo(wi.y) + bf_lo(wj.y);
            C1[3] = bf_hi(wi.y) + bf_hi(wj.y);

            const u32x4 r1 = a1p[g * 64];
            const u32x4 r2 = a2p[g * 64];
            union { bf16x8 v; unsigned u[4]; } A1, A2;
            A1.u[0] = r1.x; A1.u[1] = r1.y; A1.u[2] = r1.z; A1.u[3] = 0u;
            A2.u[0] = r2.x; A2.u[1] = r2.y; A2.u[2] = 0u;   A2.u[3] = 0u;

            const f32x4v P = __builtin_amdgcn_mfma_f32_16x16x32_bf16(A1.v, B1.v, C1, 0, 0, 0);

            union { bf16x8 v; unsigned u[4]; } B2;
            B2.u[0] = pack_bf16x2(silu_f(P[0]), silu_f(P[1]));
            B2.u[1] = pack_bf16x2(silu_f(P[2]), silu_f(P[3]));
            B2.u[2] = 0u; B2.u[3] = 0u;

            if (g & 1) acc1 = __builtin_amdgcn_mfma_f32_16x16x32_bf16(A2.v, B2.v, acc1, 0, 0, 0);
            else       acc0 = __builtin_amdgcn_mfma_f32_16x16x32_bf16(A2.v, B2.v, acc0, 0, 0, 0);
        }
    };

    __asm__ __volatile__("s_waitcnt vmcnt(0)" ::: "memory");
    run_half(0);

    __asm__ __volatile__("s_waitcnt lgkmcnt(0)" ::: "memory");
#pragma unroll
    for (int u = 0; u < 4; ++u)
        gld_lds16(si_base + 256 + (4 * u + q) * 16, (char*)myl + u * 1024);
#pragma unroll
    for (int u = 0; u < 4; ++u)
        gld_lds16(sj_base + 256 + (4 * u + q) * 16, (char*)myl + 4096 + u * 1024);
    __asm__ __volatile__("s_waitcnt vmcnt(0)" ::: "memory");
    run_half(1);

    const f32x4v accT = acc0 + acc1;
    float* op = out + BONDS_OFF + (size_t)(k0 + m) * NBT;
    if (q == 0) {
        __builtin_nontemporal_store(accT[0], op + 0);
        __builtin_nontemporal_store(accT[1], op + 1);
        __builtin_nontemporal_store(accT[2], op + 2);
        __builtin_nontemporal_store(accT[3], op + 3);
    } else if (q == 1) {
        __builtin_nontemporal_store(accT[0], op + 4);
    }
}

// ---------------------------------------------------------------------------
extern "C" void kernel_launch(void* const* d_in, const int* in_sizes, int n_in,
                              void* d_out, int out_size, void* d_ws, size_t ws_size,
                              hipStream_t stream) {
    const float* s   = (const float*)d_in[0];
    const float* e   = (const float*)d_in[1];
    const int*   eix = (const int*)d_in[3];
    const float* Wsh = (const float*)d_in[4];
    const float* bsh = (const float*)d_in[5];
    const float* Wb  = (const float*)d_in[6];
    const float* bbo = (const float*)d_in[7];
    const float* Wbs = (const float*)d_in[8];
    const float* bbs = (const float*)d_in[9];
    const float* Wa  = (const float*)d_in[10];
    const float* ba  = (const float*)d_in[11];
    float* out = (float*)d_out;

    char* ws = (char*)d_ws;
    unsigned short*     sact16 = (unsigned short*)ws;             // 2 MB @ 0
    u32x4*              A1pre  = (u32x4*)(ws + (2u << 20));       // 16 KB
    u32x4*              A2pre  = (u32x4*)(ws + (2u << 20) + 16384);
    unsigned long long* tab    = (unsigned long long*)(ws + (3u << 20)); // 8 MB

    (void)hipMemsetAsync(tab, 0x00, TSIZE * sizeof(unsigned long long), stream);

    k_gemm1<<<2049, 256, 0, stream>>>(s, Wsh, bsh, eix, Wb, bbo, Wbs,
                                      sact16, tab, A1pre, A2pre);
    k_edges_mfma<<<4672, 256, 0, stream>>>(eix, e, tab, sact16,
                                           A1pre, A2pre, bbs, Wa, ba, out);
}